// Round 5
// baseline (240.615 us; speedup 1.0000x reference)
//
#include <hip/hip_runtime.h>
#include <math.h>

#define BB 2048
#define NN 8192
#define HH 10
#define BETA 0.1f
#define NSPLIT 4
#define NPART (BB * NSPLIT)          // 8192 partial blocks
#define NFIN  (BB / 256)             // 8 finalize blocks
#define MAGIC 0x5EEDC0DEu

// Hardware transcendentals: v_log_f32 = log2(x), v_exp_f32 = 2^x (~1 ulp each).
// Valid: x = yn - y[k] > 0 for active k (y strictly increasing cumsum of positives).
__device__ __forceinline__ float fast_log2(float x) {
    float r; asm("v_log_f32 %0, %1" : "=v"(r) : "v"(x)); return r;
}
__device__ __forceinline__ float fast_exp2(float x) {
    float r; asm("v_exp_f32 %0, %1" : "=v"(r) : "v"(x)); return r;
}

__device__ __forceinline__ float alpha_of(float yp,
    const float* __restrict__ aw1, const float* __restrict__ ab1,
    const float* __restrict__ aw2, const float* __restrict__ ab2) {
    float m = ab2[0];
    #pragma unroll
    for (int h = 0; h < HH; ++h)
        m += fmaxf(fmaf(yp, aw1[h], ab1[h]), 0.f) * aw2[h];
    const float g   = 1.f - expf(-BETA * yp);
    const float sig = 1.f / (1.f + expf(-m));
    return 1.f - sig * g;
}

// Single dispatch. Blocks [0, NPART): partial sums for (row b = blk>>2, split s = blk&3).
// Split s covers waves' element windows [(w*4+s)*512, +512) -> each split of a row
// carries ~n/4 work (balanced quanta). Blocks [NPART, NPART+NFIN): finalizers that
// spin on device-scope flags, then do the per-row epilogue + output MLP.
// ws layout: u64 sm[NPART] | u64 tr[NPART] | u32 flag[NPART].
__global__ __launch_bounds__(256) void frac_fused_kernel(
    const float* __restrict__ y_plus,
    const int*   __restrict__ iidx,
    const float* __restrict__ DU,
    const float* __restrict__ Y,
    const float* __restrict__ aw1, const float* __restrict__ ab1,
    const float* __restrict__ aw2, const float* __restrict__ ab2,
    const float* __restrict__ w1,  const float* __restrict__ b1,
    const float* __restrict__ w2,  const float* __restrict__ b2,
    unsigned long long* __restrict__ ws_sm,
    unsigned long long* __restrict__ ws_tr,
    unsigned*           __restrict__ ws_flag,
    float* __restrict__ out)
{
    const int blk = blockIdx.x;
    const int tid = threadIdx.x;

    if (blk < NPART) {
        // ---------------- partial block ----------------
        const int b = blk >> 2;
        const int s = blk & 3;
        const int n = iidx[b];

        const float a = alpha_of(y_plus[b], aw1, ab1, aw2, ab2);
        const float t = 1.f - a;

        const float* yr = Y  + (size_t)b * NN;
        const float* dr = DU + (size_t)b * NN;

        const bool need_main = (a != 0.f) && (a != 1.f) && (n >= 2);
        const bool need_trap = (a == 0.f) && (n >= 1);

        float sm = 0.f, tr = 0.f;

        const int w = tid >> 6, l = tid & 63;
        const int k0 = ((((w << 2) | s) << 6) | l) << 3;   // ((w*4+s)*64 + l) * 8

        if (need_main) {
            const int kend = n - 2;                        // inclusive
            if (k0 <= kend) {
                float4 ya = *reinterpret_cast<const float4*>(yr + k0);
                float4 yb = *reinterpret_cast<const float4*>(yr + k0 + 4);
                float4 da = *reinterpret_cast<const float4*>(dr + k0);
                float4 db = *reinterpret_cast<const float4*>(dr + k0 + 4);
                float ynext = (k0 + 8 <= kend + 1) ? yr[k0 + 8] : yb.w; // <= n-1 <= 8191
                const float yn = yr[n];
                float yv[9] = {ya.x, ya.y, ya.z, ya.w, yb.x, yb.y, yb.z, yb.w, ynext};
                float dv[8] = {da.x, da.y, da.z, da.w, db.x, db.y, db.z, db.w};
                float p[9];
                #pragma unroll
                for (int j = 0; j < 9; ++j) {
                    float x = fmaxf(yn - yv[j], 1e-30f);
                    p[j] = fast_exp2(t * fast_log2(x));    // telescoped: 9 pows / 8 terms
                }
                #pragma unroll
                for (int q = 0; q < 8; ++q)
                    if (k0 + q <= kend)
                        sm = fmaf(p[q] - p[q + 1], dv[q], sm);
            }
        }
        if (need_trap) {
            const int kend = n - 1;                        // inclusive segment index
            if (k0 <= kend) {
                float4 ya = *reinterpret_cast<const float4*>(yr + k0);
                float4 yb = *reinterpret_cast<const float4*>(yr + k0 + 4);
                float4 da = *reinterpret_cast<const float4*>(dr + k0);
                float4 db = *reinterpret_cast<const float4*>(dr + k0 + 4);
                float ynext = (k0 + 8 <= kend + 1) ? yr[k0 + 8] : yb.w; // <= n <= 8191
                float dnext = (k0 + 8 <= kend + 1) ? dr[k0 + 8] : db.w;
                float yv[9] = {ya.x, ya.y, ya.z, ya.w, yb.x, yb.y, yb.z, yb.w, ynext};
                float dv[9] = {da.x, da.y, da.z, da.w, db.x, db.y, db.z, db.w, dnext};
                #pragma unroll
                for (int q = 0; q < 8; ++q)
                    if (k0 + q <= kend)
                        tr += (yv[q + 1] - yv[q]) * (dv[q + 1] + dv[q]) * 0.5f;
            }
        }

        // block reduce: wave64 shuffle then LDS across 4 waves
        double smd = (double)sm, trd = (double)tr;
        for (int off = 32; off > 0; off >>= 1) {
            smd += __shfl_down(smd, off, 64);
            trd += __shfl_down(trd, off, 64);
        }
        __shared__ double s_sm[4], s_tr[4];
        if (l == 0) { s_sm[w] = smd; s_tr[w] = trd; }
        __syncthreads();
        if (tid == 0) {
            double smT = s_sm[0] + s_sm[1] + s_sm[2] + s_sm[3];
            double trT = s_tr[0] + s_tr[1] + s_tr[2] + s_tr[3];
            // publish: values, release fence, flag (device-scope atomics)
            atomicExch(&ws_sm[blk], (unsigned long long)__double_as_longlong(smT));
            atomicExch(&ws_tr[blk], (unsigned long long)__double_as_longlong(trT));
            __threadfence();
            atomicExch(&ws_flag[blk], MAGIC);
        }
    } else {
        // ---------------- finalize block ----------------
        const int b = (blk - NPART) * 256 + tid;           // 8 blocks * 256 = 2048 rows
        const int n = iidx[b];
        const float a = alpha_of(y_plus[b], aw1, ab1, aw2, ab2);
        const float t = 1.f - a;

        double sm = 0.0, tr = 0.0;
        for (int s = 0; s < NSPLIT; ++s) {                 // fixed order -> deterministic
            const int i = b * NSPLIT + s;
            int guard = 0;
            while (atomicAdd(&ws_flag[i], 0u) != MAGIC && guard < (1 << 25)) {
                ++guard;
                __builtin_amdgcn_s_sleep(2);
            }
            __threadfence();
            sm += __longlong_as_double((long long)atomicAdd(&ws_sm[i], 0ULL));
            tr += __longlong_as_double((long long)atomicAdd(&ws_tr[i], 0ULL));
        }

        const float* yr = Y  + (size_t)b * NN;
        const float* dr = DU + (size_t)b * NN;

        float dres;
        if (a == 0.f) {
            dres = (float)tr;
        } else if (a == 1.f) {
            dres = dr[n];
        } else if (n == 0) {
            dres = 0.f;
        } else {
            float last = powf(yr[n] - yr[n - 1], t) * dr[n - 1]; // once per row: exact powf
            float fac  = expf(-lgammaf(2.f - a));
            dres = fac * ((float)sm + last);
        }
        float o = b2[0];
        #pragma unroll
        for (int h = 0; h < HH; ++h)
            o += fmaxf(fmaf(dres, w1[h], b1[h]), 0.f) * w2[h];
        out[b] = o;
    }
}

extern "C" void kernel_launch(void* const* d_in, const int* in_sizes, int n_in,
                              void* d_out, int out_size, void* d_ws, size_t ws_size,
                              hipStream_t stream) {
    const float* y_plus = (const float*)d_in[0];
    const int*   iidx   = (const int*)  d_in[1];
    const float* DU     = (const float*)d_in[2];
    const float* Y      = (const float*)d_in[3];
    const float* aw1    = (const float*)d_in[4];
    const float* ab1    = (const float*)d_in[5];
    const float* aw2    = (const float*)d_in[6];
    const float* ab2    = (const float*)d_in[7];
    const float* w1     = (const float*)d_in[8];
    const float* b1     = (const float*)d_in[9];
    const float* w2     = (const float*)d_in[10];
    const float* b2     = (const float*)d_in[11];
    float* out = (float*)d_out;

    unsigned long long* ws_sm   = (unsigned long long*)d_ws;
    unsigned long long* ws_tr   = ws_sm + NPART;
    unsigned*           ws_flag = (unsigned*)(ws_tr + NPART);

    frac_fused_kernel<<<NPART + NFIN, 256, 0, stream>>>(
        y_plus, iidx, DU, Y, aw1, ab1, aw2, ab2, w1, b1, w2, b2,
        ws_sm, ws_tr, ws_flag, out);
}

// Round 6
// 26.488 us; speedup vs baseline: 9.0838x; 9.0838x over previous
//
#include <hip/hip_runtime.h>
#include <math.h>

#define BB 2048
#define NN 8192
#define HH 10
#define BETA 0.1f

// Hardware transcendentals: v_log_f32 = log2(x), v_exp_f32 = 2^x (~1 ulp each).
// Valid: x = yn - y[k] > 0 for active k (y strictly increasing cumsum of positives);
// inactive lanes are clamped to 1e-30 and masked out of the accumulator.
__device__ __forceinline__ float fast_log2(float x) {
    float r; asm("v_log_f32 %0, %1" : "=v"(r) : "v"(x)); return r;
}
__device__ __forceinline__ float fast_exp2(float x) {
    float r; asm("v_exp_f32 %0, %1" : "=v"(r) : "v"(x)); return r;
}

// One block per row, 256 threads, FIXED 4 iterations covering all 8192 elements.
// Every block does identical work (inactive elements masked, not branched) ->
// zero CU-level load imbalance; 2048 blocks x 4 waves = exactly full residency.
__global__ __launch_bounds__(256) void frac_mlp_kernel(
    const float* __restrict__ y_plus,
    const int*   __restrict__ iidx,
    const float* __restrict__ DU,
    const float* __restrict__ Y,
    const float* __restrict__ aw1, const float* __restrict__ ab1,
    const float* __restrict__ aw2, const float* __restrict__ ab2,
    const float* __restrict__ w1,  const float* __restrict__ b1,
    const float* __restrict__ w2,  const float* __restrict__ b2,
    float* __restrict__ out)
{
    const int b   = blockIdx.x;
    const int tid = threadIdx.x;
    const int n   = iidx[b];
    const float yp = y_plus[b];

    // alpha = 1 - sigmoid(mlp(yp)) * (1 - exp(-beta*yp))   (all threads redundantly)
    float m = ab2[0];
    #pragma unroll
    for (int h = 0; h < HH; ++h)
        m += fmaxf(fmaf(yp, aw1[h], ab1[h]), 0.f) * aw2[h];
    const float g   = 1.f - expf(-BETA * yp);
    const float sig = 1.f / (1.f + expf(-m));
    const float a   = 1.f - sig * g;
    const float t   = 1.f - a;

    const float* yr = Y  + (size_t)b * NN;
    const float* dr = DU + (size_t)b * NN;
    const float yn = yr[n];

    double smd = 0.0;   // main accumulator (this thread)
    double trd = 0.0;   // trapezoid accumulator (a == 0 rows)

    if (a != 0.f) {
        const int kend = n - 2;                 // may be negative: then all masked
        #pragma unroll 1
        for (int it = 0; it < 4; ++it) {
            const int k0 = it * 2048 + tid * 8;
            float4 ya = *reinterpret_cast<const float4*>(yr + k0);
            float4 yb = *reinterpret_cast<const float4*>(yr + k0 + 4);
            float4 da = *reinterpret_cast<const float4*>(dr + k0);
            float4 db = *reinterpret_cast<const float4*>(dr + k0 + 4);
            // clamped address: k=8191 is always masked (kend <= 8190), value unused
            float ynext = yr[min(k0 + 8, NN - 1)];
            float yv[9] = {ya.x, ya.y, ya.z, ya.w, yb.x, yb.y, yb.z, yb.w, ynext};
            float dv[8] = {da.x, da.y, da.z, da.w, db.x, db.y, db.z, db.w};
            float p[9];
            #pragma unroll
            for (int j = 0; j < 9; ++j) {
                float x = fmaxf(yn - yv[j], 1e-30f);
                p[j] = fast_exp2(t * fast_log2(x));   // telescoped: 9 pows / 8 terms
            }
            float acc = 0.f;
            #pragma unroll
            for (int q = 0; q < 8; ++q) {
                float term = (k0 + q <= kend) ? dv[q] : 0.f;   // mask, no branch
                acc = fmaf(p[q] - p[q + 1], term, acc);
            }
            smd += (double)acc;
        }
    } else {
        const int kend = n - 1;                 // trapezoid segments, kend <= 8190
        #pragma unroll 1
        for (int it = 0; it < 4; ++it) {
            const int k0 = it * 2048 + tid * 8;
            float4 ya = *reinterpret_cast<const float4*>(yr + k0);
            float4 yb = *reinterpret_cast<const float4*>(yr + k0 + 4);
            float4 da = *reinterpret_cast<const float4*>(dr + k0);
            float4 db = *reinterpret_cast<const float4*>(dr + k0 + 4);
            float ynext = yr[min(k0 + 8, NN - 1)];
            float dnext = dr[min(k0 + 8, NN - 1)];
            float yv[9] = {ya.x, ya.y, ya.z, ya.w, yb.x, yb.y, yb.z, yb.w, ynext};
            float dv[9] = {da.x, da.y, da.z, da.w, db.x, db.y, db.z, db.w, dnext};
            float acc = 0.f;
            #pragma unroll
            for (int q = 0; q < 8; ++q) {
                float seg = (yv[q + 1] - yv[q]) * (dv[q + 1] + dv[q]) * 0.5f;
                acc += (k0 + q <= kend) ? seg : 0.f;           // mask, no branch
            }
            trd += (double)acc;
        }
    }

    // block reduction: wave64 shuffle, then LDS across the 4 waves
    for (int off = 32; off > 0; off >>= 1) {
        smd += __shfl_down(smd, off, 64);
        trd += __shfl_down(trd, off, 64);
    }
    __shared__ double s_sm[4], s_tr[4];
    const int wave = tid >> 6, lane = tid & 63;
    if (lane == 0) { s_sm[wave] = smd; s_tr[wave] = trd; }
    __syncthreads();

    if (tid == 0) {
        double smT = s_sm[0] + s_sm[1] + s_sm[2] + s_sm[3];
        double trT = s_tr[0] + s_tr[1] + s_tr[2] + s_tr[3];
        float dres;
        if (a == 0.f) {
            dres = (float)trT;
        } else if (a == 1.f) {
            dres = dr[n];
        } else if (n == 0) {
            dres = 0.f;
        } else {
            float last = powf(yn - yr[n - 1], t) * dr[n - 1];  // once per row: exact powf
            float fac  = expf(-lgammaf(2.f - a));
            dres = fac * ((float)smT + last);
        }
        float o = b2[0];
        #pragma unroll
        for (int h = 0; h < HH; ++h)
            o += fmaxf(fmaf(dres, w1[h], b1[h]), 0.f) * w2[h];
        out[b] = o;
    }
}

extern "C" void kernel_launch(void* const* d_in, const int* in_sizes, int n_in,
                              void* d_out, int out_size, void* d_ws, size_t ws_size,
                              hipStream_t stream) {
    const float* y_plus = (const float*)d_in[0];
    const int*   iidx   = (const int*)  d_in[1];
    const float* DU     = (const float*)d_in[2];
    const float* Y      = (const float*)d_in[3];
    const float* aw1    = (const float*)d_in[4];
    const float* ab1    = (const float*)d_in[5];
    const float* aw2    = (const float*)d_in[6];
    const float* ab2    = (const float*)d_in[7];
    const float* w1     = (const float*)d_in[8];
    const float* b1     = (const float*)d_in[9];
    const float* w2     = (const float*)d_in[10];
    const float* b2     = (const float*)d_in[11];
    float* out = (float*)d_out;

    frac_mlp_kernel<<<BB, 256, 0, stream>>>(y_plus, iidx, DU, Y,
                                            aw1, ab1, aw2, ab2,
                                            w1, b1, w2, b2, out);
}

// Round 7
// 18.164 us; speedup vs baseline: 13.2467x; 1.4583x over previous
//
#include <hip/hip_runtime.h>
#include <math.h>

#define BB 2048
#define NN 8192
#define HH 10
#define BETA 0.1f

// Hardware transcendentals: v_log_f32 = log2(x), v_exp_f32 = 2^x (~1 ulp each).
// Valid: x = yn - y[k] > 0 for active k (y strictly increasing cumsum of positives).
__device__ __forceinline__ float fast_log2(float x) {
    float r; asm("v_log_f32 %0, %1" : "=v"(r) : "v"(x)); return r;
}
__device__ __forceinline__ float fast_exp2(float x) {
    float r; asm("v_exp_f32 %0, %1" : "=v"(r) : "v"(x)); return r;
}

// One block per row, 512 threads (8 waves), up to 2 iterations of 8 elems/thread.
// 2048 blocks x 8 waves = 16384 waves = 2x device wave capacity -> two rounds with
// dynamic backfill: short-row blocks retire early and waiting blocks take their
// slots, shrinking the CU-level straggler tail that a fully-resident grid (R2)
// cannot avoid. Active-only reads preserved (L3-resident working set).
__global__ __launch_bounds__(512) void frac_mlp_kernel(
    const float* __restrict__ y_plus,
    const int*   __restrict__ iidx,
    const float* __restrict__ DU,
    const float* __restrict__ Y,
    const float* __restrict__ aw1, const float* __restrict__ ab1,
    const float* __restrict__ aw2, const float* __restrict__ ab2,
    const float* __restrict__ w1,  const float* __restrict__ b1,
    const float* __restrict__ w2,  const float* __restrict__ b2,
    float* __restrict__ out)
{
    const int b   = blockIdx.x;
    const int tid = threadIdx.x;
    const int n   = iidx[b];
    const float yp = y_plus[b];

    // alpha = 1 - sigmoid(mlp(yp)) * (1 - exp(-beta*yp))   (all threads redundantly)
    float m = ab2[0];
    #pragma unroll
    for (int h = 0; h < HH; ++h)
        m += fmaxf(fmaf(yp, aw1[h], ab1[h]), 0.f) * aw2[h];
    const float g   = 1.f - expf(-BETA * yp);
    const float sig = 1.f / (1.f + expf(-m));
    const float a   = 1.f - sig * g;
    const float t   = 1.f - a;

    const float* yr = Y  + (size_t)b * NN;
    const float* dr = DU + (size_t)b * NN;
    const float yn = yr[n];

    const bool need_main = (a != 0.f) && (a != 1.f) && (n >= 2);
    const bool need_trap = (a == 0.f) && (n >= 1);

    float sm = 0.f;   // main partial (this thread)
    float tr = 0.f;   // trapezoid partial

    if (need_main) {
        const int kend = n - 2;                       // inclusive
        for (int k0 = tid * 8; k0 <= kend; k0 += 512 * 8) {
            float4 ya = *reinterpret_cast<const float4*>(yr + k0);
            float4 yb = *reinterpret_cast<const float4*>(yr + k0 + 4);
            float4 da = *reinterpret_cast<const float4*>(dr + k0);
            float4 db = *reinterpret_cast<const float4*>(dr + k0 + 4);
            float ynext = (k0 + 8 <= kend + 1) ? yr[k0 + 8] : yb.w;  // k0+8 <= n-1 <= 8191
            float yv[9] = {ya.x, ya.y, ya.z, ya.w, yb.x, yb.y, yb.z, yb.w, ynext};
            float dv[8] = {da.x, da.y, da.z, da.w, db.x, db.y, db.z, db.w};
            float p[9];
            #pragma unroll
            for (int j = 0; j < 9; ++j) {
                float x = fmaxf(yn - yv[j], 1e-30f);
                p[j] = fast_exp2(t * fast_log2(x));   // telescoped: 9 pows / 8 terms
            }
            #pragma unroll
            for (int q = 0; q < 8; ++q)
                if (k0 + q <= kend)
                    sm = fmaf(p[q] - p[q + 1], dv[q], sm);
        }
    }
    if (need_trap) {
        const int kend = n - 1;                       // inclusive segment index
        for (int k0 = tid * 8; k0 <= kend; k0 += 512 * 8) {
            float4 ya = *reinterpret_cast<const float4*>(yr + k0);
            float4 yb = *reinterpret_cast<const float4*>(yr + k0 + 4);
            float4 da = *reinterpret_cast<const float4*>(dr + k0);
            float4 db = *reinterpret_cast<const float4*>(dr + k0 + 4);
            float ynext = (k0 + 8 <= kend + 1) ? yr[k0 + 8] : yb.w;  // k0+8 <= n <= 8191
            float dnext = (k0 + 8 <= kend + 1) ? dr[k0 + 8] : db.w;
            float yv[9] = {ya.x, ya.y, ya.z, ya.w, yb.x, yb.y, yb.z, yb.w, ynext};
            float dv[9] = {da.x, da.y, da.z, da.w, db.x, db.y, db.z, db.w, dnext};
            #pragma unroll
            for (int q = 0; q < 8; ++q)
                if (k0 + q <= kend)
                    tr += (yv[q + 1] - yv[q]) * (dv[q + 1] + dv[q]) * 0.5f;
        }
    }

    // block reduction: wave64 shuffle, then LDS across the 8 waves
    double smd = (double)sm, trd = (double)tr;
    for (int off = 32; off > 0; off >>= 1) {
        smd += __shfl_down(smd, off, 64);
        trd += __shfl_down(trd, off, 64);
    }
    __shared__ double s_sm[8], s_tr[8];
    const int wave = tid >> 6, lane = tid & 63;
    if (lane == 0) { s_sm[wave] = smd; s_tr[wave] = trd; }
    __syncthreads();

    if (tid == 0) {
        double smT = 0.0, trT = 0.0;
        #pragma unroll
        for (int w = 0; w < 8; ++w) { smT += s_sm[w]; trT += s_tr[w]; }
        float dres;
        if (a == 0.f) {
            dres = (float)trT;
        } else if (a == 1.f) {
            dres = dr[n];
        } else if (n == 0) {
            dres = 0.f;
        } else {
            float last = powf(yn - yr[n - 1], t) * dr[n - 1];  // once per row: exact powf
            float fac  = expf(-lgammaf(2.f - a));
            dres = fac * ((float)smT + last);
        }
        float o = b2[0];
        #pragma unroll
        for (int h = 0; h < HH; ++h)
            o += fmaxf(fmaf(dres, w1[h], b1[h]), 0.f) * w2[h];
        out[b] = o;
    }
}

extern "C" void kernel_launch(void* const* d_in, const int* in_sizes, int n_in,
                              void* d_out, int out_size, void* d_ws, size_t ws_size,
                              hipStream_t stream) {
    const float* y_plus = (const float*)d_in[0];
    const int*   iidx   = (const int*)  d_in[1];
    const float* DU     = (const float*)d_in[2];
    const float* Y      = (const float*)d_in[3];
    const float* aw1    = (const float*)d_in[4];
    const float* ab1    = (const float*)d_in[5];
    const float* aw2    = (const float*)d_in[6];
    const float* ab2    = (const float*)d_in[7];
    const float* w1     = (const float*)d_in[8];
    const float* b1     = (const float*)d_in[9];
    const float* w2     = (const float*)d_in[10];
    const float* b2     = (const float*)d_in[11];
    float* out = (float*)d_out;

    frac_mlp_kernel<<<BB, 512, 0, stream>>>(y_plus, iidx, DU, Y,
                                            aw1, ab1, aw2, ab2,
                                            w1, b1, w2, b2, out);
}

// Round 8
// 17.947 us; speedup vs baseline: 13.4069x; 1.0121x over previous
//
#include <hip/hip_runtime.h>
#include <math.h>

#define BB 2048
#define NN 8192
#define HH 10
#define BETA 0.1f

// Hardware transcendentals: v_log_f32 = log2(x), v_exp_f32 = 2^x (~1 ulp each).
// Valid: x = yn - y[k] > 0 for active k (y strictly increasing cumsum of positives).
__device__ __forceinline__ float fast_log2(float x) {
    float r; asm("v_log_f32 %0, %1" : "=v"(r) : "v"(x)); return r;
}
__device__ __forceinline__ float fast_exp2(float x) {
    float r; asm("v_exp_f32 %0, %1" : "=v"(r) : "v"(x)); return r;
}

// One block per row, 512 threads (8 waves). Thread t owns elements [8t, 8t+8) and
// [8t+4096, 8t+4104): exactly 2 peeled stages. Both stages' loads are issued
// (exec-masked, active-only) BEFORE stage-1 compute -> one latency exposure
// instead of two serialized ones. 2048 x 8 waves = 2 residency rounds with
// dynamic backfill (R7's balance win preserved).
__global__ __launch_bounds__(512) void frac_mlp_kernel(
    const float* __restrict__ y_plus,
    const int*   __restrict__ iidx,
    const float* __restrict__ DU,
    const float* __restrict__ Y,
    const float* __restrict__ aw1, const float* __restrict__ ab1,
    const float* __restrict__ aw2, const float* __restrict__ ab2,
    const float* __restrict__ w1,  const float* __restrict__ b1,
    const float* __restrict__ w2,  const float* __restrict__ b2,
    float* __restrict__ out)
{
    const int b   = blockIdx.x;
    const int tid = threadIdx.x;
    const int n   = iidx[b];
    const float yp = y_plus[b];

    const float* yr = Y  + (size_t)b * NN;
    const float* dr = DU + (size_t)b * NN;
    const float yn = yr[n];                    // independent: issue before alpha MLP

    // alpha = 1 - sigmoid(mlp(yp)) * (1 - exp(-beta*yp))   (all threads redundantly)
    float m = ab2[0];
    #pragma unroll
    for (int h = 0; h < HH; ++h)
        m += fmaxf(fmaf(yp, aw1[h], ab1[h]), 0.f) * aw2[h];
    const float g   = 1.f - expf(-BETA * yp);
    const float sig = 1.f / (1.f + expf(-m));
    const float a   = 1.f - sig * g;
    const float t   = 1.f - a;

    const bool need_main = (a != 0.f) && (a != 1.f) && (n >= 2);
    const bool need_trap = (a == 0.f) && (n >= 1);

    float sm = 0.f;   // main partial (this thread)
    float tr = 0.f;   // trapezoid partial

    if (need_main) {
        const int kend = n - 2;                       // inclusive
        const int k0 = tid * 8;                       // [0, 4088]
        const int k1 = k0 + 4096;                     // [4096, 8184]
        const bool act0 = (k0 <= kend);
        const bool act1 = (k1 <= kend);

        float4 ya0, yb0, da0, db0, ya1, yb1, da1, db1;
        float ynext0 = 0.f, ynext1 = 0.f;

        // ---- issue ALL loads first (exec-masked: only active lanes fetch) ----
        if (act0) {
            ya0 = *reinterpret_cast<const float4*>(yr + k0);
            yb0 = *reinterpret_cast<const float4*>(yr + k0 + 4);
            da0 = *reinterpret_cast<const float4*>(dr + k0);
            db0 = *reinterpret_cast<const float4*>(dr + k0 + 4);
            ynext0 = yr[k0 + 8];                      // k0+8 <= 4096: always in-bounds;
        }                                             // value masked when unneeded
        if (act1) {
            ya1 = *reinterpret_cast<const float4*>(yr + k1);
            yb1 = *reinterpret_cast<const float4*>(yr + k1 + 4);
            da1 = *reinterpret_cast<const float4*>(dr + k1);
            db1 = *reinterpret_cast<const float4*>(dr + k1 + 4);
            // k1+8 can be 8192 (OOB for last row); fallback never used (masked)
            ynext1 = (k1 + 8 <= NN - 1) ? yr[k1 + 8] : yb1.w;
        }

        // ---- stage 1 compute ----
        if (act0) {
            float yv[9] = {ya0.x, ya0.y, ya0.z, ya0.w, yb0.x, yb0.y, yb0.z, yb0.w, ynext0};
            float dv[8] = {da0.x, da0.y, da0.z, da0.w, db0.x, db0.y, db0.z, db0.w};
            float p[9];
            #pragma unroll
            for (int j = 0; j < 9; ++j) {
                float x = fmaxf(yn - yv[j], 1e-30f);
                p[j] = fast_exp2(t * fast_log2(x));   // telescoped: 9 pows / 8 terms
            }
            #pragma unroll
            for (int q = 0; q < 8; ++q) {
                float term = (k0 + q <= kend) ? dv[q] : 0.f;
                sm = fmaf(p[q] - p[q + 1], term, sm);
            }
        }
        // ---- stage 2 compute ----
        if (act1) {
            float yv[9] = {ya1.x, ya1.y, ya1.z, ya1.w, yb1.x, yb1.y, yb1.z, yb1.w, ynext1};
            float dv[8] = {da1.x, da1.y, da1.z, da1.w, db1.x, db1.y, db1.z, db1.w};
            float p[9];
            #pragma unroll
            for (int j = 0; j < 9; ++j) {
                float x = fmaxf(yn - yv[j], 1e-30f);
                p[j] = fast_exp2(t * fast_log2(x));
            }
            #pragma unroll
            for (int q = 0; q < 8; ++q) {
                float term = (k1 + q <= kend) ? dv[q] : 0.f;
                sm = fmaf(p[q] - p[q + 1], term, sm);
            }
        }
    }
    if (need_trap) {
        const int kend = n - 1;                       // inclusive segment index
        for (int k0 = tid * 8; k0 <= kend; k0 += 512 * 8) {
            float4 ya = *reinterpret_cast<const float4*>(yr + k0);
            float4 yb = *reinterpret_cast<const float4*>(yr + k0 + 4);
            float4 da = *reinterpret_cast<const float4*>(dr + k0);
            float4 db = *reinterpret_cast<const float4*>(dr + k0 + 4);
            float ynext = (k0 + 8 <= kend + 1) ? yr[k0 + 8] : yb.w;  // k0+8 <= n <= 8191
            float dnext = (k0 + 8 <= kend + 1) ? dr[k0 + 8] : db.w;
            float yv[9] = {ya.x, ya.y, ya.z, ya.w, yb.x, yb.y, yb.z, yb.w, ynext};
            float dv[9] = {da.x, da.y, da.z, da.w, db.x, db.y, db.z, db.w, dnext};
            #pragma unroll
            for (int q = 0; q < 8; ++q)
                if (k0 + q <= kend)
                    tr += (yv[q + 1] - yv[q]) * (dv[q + 1] + dv[q]) * 0.5f;
        }
    }

    // block reduction: wave64 shuffle, then LDS across the 8 waves
    double smd = (double)sm, trd = (double)tr;
    for (int off = 32; off > 0; off >>= 1) {
        smd += __shfl_down(smd, off, 64);
        trd += __shfl_down(trd, off, 64);
    }
    __shared__ double s_sm[8], s_tr[8];
    const int wave = tid >> 6, lane = tid & 63;
    if (lane == 0) { s_sm[wave] = smd; s_tr[wave] = trd; }
    __syncthreads();

    if (tid == 0) {
        double smT = 0.0, trT = 0.0;
        #pragma unroll
        for (int w = 0; w < 8; ++w) { smT += s_sm[w]; trT += s_tr[w]; }
        float dres;
        if (a == 0.f) {
            dres = (float)trT;
        } else if (a == 1.f) {
            dres = dr[n];
        } else if (n == 0) {
            dres = 0.f;
        } else {
            float last = powf(yn - yr[n - 1], t) * dr[n - 1];  // once per row: exact powf
            float fac  = expf(-lgammaf(2.f - a));
            dres = fac * ((float)smT + last);
        }
        float o = b2[0];
        #pragma unroll
        for (int h = 0; h < HH; ++h)
            o += fmaxf(fmaf(dres, w1[h], b1[h]), 0.f) * w2[h];
        out[b] = o;
    }
}

extern "C" void kernel_launch(void* const* d_in, const int* in_sizes, int n_in,
                              void* d_out, int out_size, void* d_ws, size_t ws_size,
                              hipStream_t stream) {
    const float* y_plus = (const float*)d_in[0];
    const int*   iidx   = (const int*)  d_in[1];
    const float* DU     = (const float*)d_in[2];
    const float* Y      = (const float*)d_in[3];
    const float* aw1    = (const float*)d_in[4];
    const float* ab1    = (const float*)d_in[5];
    const float* aw2    = (const float*)d_in[6];
    const float* ab2    = (const float*)d_in[7];
    const float* w1     = (const float*)d_in[8];
    const float* b1     = (const float*)d_in[9];
    const float* w2     = (const float*)d_in[10];
    const float* b2     = (const float*)d_in[11];
    float* out = (float*)d_out;

    frac_mlp_kernel<<<BB, 512, 0, stream>>>(y_plus, iidx, DU, Y,
                                            aw1, ab1, aw2, ab2,
                                            w1, b1, w2, b2, out);
}